// Round 1
// baseline (777.056 us; speedup 1.0000x reference)
//
#include <hip/hip_runtime.h>
#include <math.h>

#define N_NODES 100000
#define N_EDGES 1600000
#define F_IN 16
#define HDIM 64
#define E_DIM 9
#define NEG 0.2f

// ---- K1: h = x@W (wave per node), a_src = h@att_src, a_dst = h@att_dst ----
__global__ __launch_bounds__(256) void k_node_h(
    const float* __restrict__ x, const float* __restrict__ W,
    const float* __restrict__ att_src, const float* __restrict__ att_dst,
    float* __restrict__ h, float* __restrict__ a_src, float* __restrict__ a_dst) {
  __shared__ float sW[F_IN * HDIM];
  int t = threadIdx.x;
  for (int i = t; i < F_IN * HDIM; i += 256) sW[i] = W[i];
  __syncthreads();
  int lane = t & 63;
  int node = blockIdx.x * 4 + (t >> 6);
  if (node >= N_NODES) return;
  const float* xr = x + node * F_IN;
  float acc = 0.f;
#pragma unroll
  for (int k = 0; k < F_IN; ++k) acc += xr[k] * sW[k * HDIM + lane];
  h[node * HDIM + lane] = acc;
  float v1 = acc * att_src[lane];
  float v2 = acc * att_dst[lane];
#pragma unroll
  for (int off = 32; off > 0; off >>= 1) {
    v1 += __shfl_down(v1, off);
    v2 += __shfl_down(v2, off);
  }
  if (lane == 0) { a_src[node] = v1; a_dst[node] = v2; }
}

// ---- tiny: w_e[d] = sum_h W_edge[d,h]*att_edge[h] ----
__global__ void k_we(const float* __restrict__ W_edge,
                     const float* __restrict__ att_edge, float* __restrict__ w_e) {
  int d = threadIdx.x;
  if (d < E_DIM) {
    float s = 0.f;
    for (int hh = 0; hh < HDIM; ++hh) s += W_edge[d * HDIM + hh] * att_edge[hh];
    w_e[d] = s;
  }
}

// ---- K2: per-edge logits -> exp, plus scalar segment sums (denom, sum_ae, deg) ----
__global__ __launch_bounds__(256) void k_edge1(
    const float* __restrict__ ea, const int* __restrict__ ei,
    const float* __restrict__ w_e, const float* __restrict__ a_src,
    const float* __restrict__ a_dst, float* __restrict__ exbuf,
    float* __restrict__ denom, float* __restrict__ sum_ae, float* __restrict__ deg) {
  __shared__ float swe[E_DIM];
  if (threadIdx.x < E_DIM) swe[threadIdx.x] = w_e[threadIdx.x];
  __syncthreads();
  int e = blockIdx.x * 256 + threadIdx.x;
  if (e >= N_EDGES) return;
  int s = ei[e];
  int d = ei[N_EDGES + e];
  float a_e = 0.f;
#pragma unroll
  for (int k = 0; k < E_DIM; ++k) a_e += ea[e * E_DIM + k] * swe[k];
  float al = a_src[s] + a_dst[d] + a_e;
  al = al >= 0.f ? al : NEG * al;
  float ee = expf(al);          // softmax shift-invariance: max-subtraction skipped
  exbuf[e] = ee;
  atomicAdd(denom + d, ee);
  atomicAdd(sum_ae + d, a_e);
  atomicAdd(deg + d, 1.f);
}

// ---- K3: self-loop term, inverse denominator, init accumulator with self-loop msg ----
__global__ __launch_bounds__(256) void k_node_loop(
    const float* __restrict__ h, const float* __restrict__ a_src,
    const float* __restrict__ a_dst, const float* __restrict__ sum_ae,
    const float* __restrict__ deg, const float* __restrict__ denom,
    float* __restrict__ inv_denom, float* __restrict__ out_acc) {
  int t = threadIdx.x;
  int lane = t & 63;
  int node = blockIdx.x * 4 + (t >> 6);
  if (node >= N_NODES) return;
  // uniform scalar loads (broadcast) — every lane computes the same values
  float al = a_src[node] + a_dst[node] + sum_ae[node] / fmaxf(deg[node], 1.f);
  al = al >= 0.f ? al : NEG * al;
  float exl = expf(al);
  float inv = 1.f / (denom[node] + exl + 1e-16f);
  if (lane == 0) inv_denom[node] = inv;
  float coef = exl * inv;
  out_acc[node * HDIM + lane] = h[node * HDIM + lane] * coef;
}

// ---- K4: wave per edge — scatter h[src]*alpha into out_acc[dst] (64-lane atomics) ----
__global__ __launch_bounds__(256) void k_edge2(
    const int* __restrict__ ei, const float* __restrict__ exbuf,
    const float* __restrict__ inv_denom, const float* __restrict__ h,
    float* __restrict__ out_acc) {
  int t = threadIdx.x;
  int lane = t & 63;
  int e = blockIdx.x * 4 + (t >> 6);
  if (e >= N_EDGES) return;
  int s = ei[e];
  int d = ei[N_EDGES + e];
  float coef = exbuf[e] * inv_denom[d];
  atomicAdd(out_acc + (size_t)d * HDIM + lane, h[(size_t)s * HDIM + lane] * coef);
}

// ---- K5: s[n] = relu(out_acc[n]+bias) . lin_w  (wave per node) ----
__global__ __launch_bounds__(256) void k_node_s(
    const float* __restrict__ out_acc, const float* __restrict__ bias,
    const float* __restrict__ lin_w, float* __restrict__ s_node) {
  int t = threadIdx.x;
  int lane = t & 63;
  int node = blockIdx.x * 4 + (t >> 6);
  if (node >= N_NODES) return;
  float v = fmaxf(out_acc[node * HDIM + lane] + bias[lane], 0.f) * lin_w[lane];
#pragma unroll
  for (int off = 32; off > 0; off >>= 1) v += __shfl_down(v, off);
  if (lane == 0) s_node[node] = v;
}

// ---- K6: out[e] = sigmoid(0.5*(s[src]+s[dst]) + lin_b) ----
__global__ __launch_bounds__(256) void k_out(
    const int* __restrict__ ei, const float* __restrict__ s_node,
    const float* __restrict__ lin_b, float* __restrict__ out) {
  int e = blockIdx.x * 256 + threadIdx.x;
  if (e >= N_EDGES) return;
  int s = ei[e];
  int d = ei[N_EDGES + e];
  float z = 0.5f * (s_node[s] + s_node[d]) + lin_b[0];
  out[e] = 1.f / (1.f + expf(-z));
}

extern "C" void kernel_launch(void* const* d_in, const int* in_sizes, int n_in,
                              void* d_out, int out_size, void* d_ws, size_t ws_size,
                              hipStream_t stream) {
  const float* x        = (const float*)d_in[0];
  const float* edge_attr= (const float*)d_in[1];
  const float* W        = (const float*)d_in[2];
  const float* W_edge   = (const float*)d_in[3];
  const float* att_src  = (const float*)d_in[4];
  const float* att_dst  = (const float*)d_in[5];
  const float* att_edge = (const float*)d_in[6];
  const float* bias     = (const float*)d_in[7];
  const float* lin_w    = (const float*)d_in[8];
  const float* lin_b    = (const float*)d_in[9];
  const int*   ei       = (const int*)d_in[10];
  float* out = (float*)d_out;

  // workspace layout (floats); total ~15.1M floats ~= 60.5 MB
  float* ws      = (float*)d_ws;
  float* h       = ws;                              // N*H
  float* out_acc = h + (size_t)N_NODES * HDIM;      // N*H
  float* a_src   = out_acc + (size_t)N_NODES * HDIM;// N
  float* a_dst   = a_src + N_NODES;                 // N
  float* sum_ae  = a_dst + N_NODES;                 // N  (zeroed)
  float* deg     = sum_ae + N_NODES;                // N  (zeroed)
  float* denom   = deg + N_NODES;                   // N  (zeroed)
  float* inv_d   = denom + N_NODES;                 // N
  float* s_node  = inv_d + N_NODES;                 // N
  float* exbuf   = s_node + N_NODES;                // E
  float* w_e     = exbuf + N_EDGES;                 // 16

  hipMemsetAsync(sum_ae, 0, sizeof(float) * 3 * N_NODES, stream);

  int nb_node   = (N_NODES + 3) / 4;     // wave per node, 4 waves/block
  int nb_edge_t = (N_EDGES + 255) / 256; // thread per edge
  int nb_edge_w = (N_EDGES + 3) / 4;     // wave per edge

  k_node_h <<<nb_node, 256, 0, stream>>>(x, W, att_src, att_dst, h, a_src, a_dst);
  k_we     <<<1, 64, 0, stream>>>(W_edge, att_edge, w_e);
  k_edge1  <<<nb_edge_t, 256, 0, stream>>>(edge_attr, ei, w_e, a_src, a_dst,
                                           exbuf, denom, sum_ae, deg);
  k_node_loop<<<nb_node, 256, 0, stream>>>(h, a_src, a_dst, sum_ae, deg, denom,
                                           inv_d, out_acc);
  k_edge2  <<<nb_edge_w, 256, 0, stream>>>(ei, exbuf, inv_d, h, out_acc);
  k_node_s <<<nb_node, 256, 0, stream>>>(out_acc, bias, lin_w, s_node);
  k_out    <<<nb_edge_t, 256, 0, stream>>>(ei, s_node, lin_b, out);
}

// Round 2
// 651.443 us; speedup vs baseline: 1.1928x; 1.1928x over previous
//
#include <hip/hip_runtime.h>
#include <math.h>

#define N_NODES 100000
#define N_EDGES 1600000
#define F_IN 16
#define HDIM 64
#define E_DIM 9
#define NEG 0.2f

// ---- K1: h = x@W (wave per node), a_src = h@att_src, a_dst = h@att_dst ----
__global__ __launch_bounds__(256) void k_node_h(
    const float* __restrict__ x, const float* __restrict__ W,
    const float* __restrict__ att_src, const float* __restrict__ att_dst,
    float* __restrict__ h, float* __restrict__ a_src, float* __restrict__ a_dst) {
  __shared__ float sW[F_IN * HDIM];
  int t = threadIdx.x;
  for (int i = t; i < F_IN * HDIM; i += 256) sW[i] = W[i];
  __syncthreads();
  int lane = t & 63;
  int node = blockIdx.x * 4 + (t >> 6);
  if (node >= N_NODES) return;
  const float* xr = x + node * F_IN;
  float acc = 0.f;
#pragma unroll
  for (int k = 0; k < F_IN; ++k) acc += xr[k] * sW[k * HDIM + lane];
  h[node * HDIM + lane] = acc;
  float v1 = acc * att_src[lane];
  float v2 = acc * att_dst[lane];
#pragma unroll
  for (int off = 32; off > 0; off >>= 1) {
    v1 += __shfl_down(v1, off);
    v2 += __shfl_down(v2, off);
  }
  if (lane == 0) { a_src[node] = v1; a_dst[node] = v2; }
}

// ---- tiny: w_e[d] = sum_h W_edge[d,h]*att_edge[h] ----
__global__ void k_we(const float* __restrict__ W_edge,
                     const float* __restrict__ att_edge, float* __restrict__ w_e) {
  int d = threadIdx.x;
  if (d < E_DIM) {
    float s = 0.f;
    for (int hh = 0; hh < HDIM; ++hh) s += W_edge[d * HDIM + hh] * att_edge[hh];
    w_e[d] = s;
  }
}

// ---- K2: count in-degree (u32, 400 KB array -> L2-resident atomics) ----
__global__ __launch_bounds__(256) void k_deg(
    const int* __restrict__ ei, unsigned* __restrict__ deg) {
  int e = blockIdx.x * 256 + threadIdx.x;
  if (e >= N_EDGES) return;
  atomicAdd(deg + ei[N_EDGES + e], 1u);
}

// ---- K3: exclusive scan of deg -> row_ptr (single block, 1024 threads) ----
__global__ __launch_bounds__(1024) void k_scan(
    const unsigned* __restrict__ deg, unsigned* __restrict__ row_ptr) {
  const int T = 1024;
  const int chunk = (N_NODES + T - 1) / T;  // 98
  int t = threadIdx.x;
  int lane = t & 63, wid = t >> 6;
  int begin = t * chunk;
  int end = begin + chunk < N_NODES ? begin + chunk : N_NODES;
  unsigned local = 0;
  for (int i = begin; i < end; ++i) local += deg[i];
  // intra-wave inclusive scan
  unsigned v = local;
#pragma unroll
  for (int off = 1; off < 64; off <<= 1) {
    unsigned u = __shfl_up(v, off, 64);
    if (lane >= off) v += u;
  }
  __shared__ unsigned wsums[16];
  if (lane == 63) wsums[wid] = v;
  __syncthreads();
  if (t == 0) {
    unsigned a = 0;
    for (int i = 0; i < 16; ++i) { unsigned tmp = wsums[i]; wsums[i] = a; a += tmp; }
  }
  __syncthreads();
  unsigned run = wsums[wid] + v - local;  // exclusive prefix for this thread
  for (int i = begin; i < end; ++i) { row_ptr[i] = run; run += deg[i]; }
}

// ---- K4: bucket edges by dst; compute a_e inline.
// atomicAdd on row_ptr[d] itself: afterwards row_ptr[d] = start of bucket d+1,
// so bucket d spans [d ? row_ptr[d-1] : 0, row_ptr[d]). ----
__global__ __launch_bounds__(256) void k_bucket(
    const float* __restrict__ ea, const int* __restrict__ ei,
    const float* __restrict__ w_e, unsigned* __restrict__ row_ptr,
    int* __restrict__ bsrc, float* __restrict__ bae) {
  __shared__ float swe[E_DIM];
  if (threadIdx.x < E_DIM) swe[threadIdx.x] = w_e[threadIdx.x];
  __syncthreads();
  int e = blockIdx.x * 256 + threadIdx.x;
  if (e >= N_EDGES) return;
  int s = ei[e];
  int d = ei[N_EDGES + e];
  float a_e = 0.f;
#pragma unroll
  for (int k = 0; k < E_DIM; ++k) a_e += ea[e * E_DIM + k] * swe[k];
  unsigned pos = atomicAdd(row_ptr + d, 1u);
  bsrc[pos] = s;
  bae[pos] = a_e;
}

// ---- K5: fused gather: softmax + aggregate + relu/bias + lin_w dot (wave/node) ----
__global__ __launch_bounds__(256) void k_gather(
    const unsigned* __restrict__ row_ptr, const int* __restrict__ bsrc,
    const float* __restrict__ bae, const float* __restrict__ h,
    const float* __restrict__ a_src, const float* __restrict__ a_dst,
    const float* __restrict__ bias, const float* __restrict__ lin_w,
    float* __restrict__ s_node) {
  int t = threadIdx.x;
  int lane = t & 63;
  int node = blockIdx.x * 4 + (t >> 6);
  if (node >= N_NODES) return;
  float adst = a_dst[node];
  unsigned start = node ? row_ptr[node - 1] : 0u;
  unsigned stop = row_ptr[node];
  float acc = 0.f, denom = 0.f, sumae = 0.f;
  for (unsigned k = start; k < stop; ++k) {
    int s = bsrc[k];            // broadcast (all lanes same addr)
    float ae = bae[k];
    float al = a_src[s] + adst + ae;
    al = al >= 0.f ? al : NEG * al;
    float ee = expf(al);        // shift-invariant softmax: max-subtract skipped
    denom += ee;
    sumae += ae;
    acc += ee * h[(size_t)s * HDIM + lane];
  }
  // self-loop: fill_value='mean' -> loop attr logit = mean of incident a_e
  float cnt = (float)(stop - start);
  float all = a_src[node] + adst + sumae / fmaxf(cnt, 1.f);
  all = all >= 0.f ? all : NEG * all;
  float eel = expf(all);
  denom += eel;
  acc += eel * h[(size_t)node * HDIM + lane];
  float o = fmaxf(acc / (denom + 1e-16f) + bias[lane], 0.f) * lin_w[lane];
#pragma unroll
  for (int off = 32; off > 0; off >>= 1) o += __shfl_down(o, off);
  if (lane == 0) s_node[node] = o;
}

// ---- K6: out[e] = sigmoid(0.5*(s[src]+s[dst]) + lin_b) ----
__global__ __launch_bounds__(256) void k_out(
    const int* __restrict__ ei, const float* __restrict__ s_node,
    const float* __restrict__ lin_b, float* __restrict__ out) {
  int e = blockIdx.x * 256 + threadIdx.x;
  if (e >= N_EDGES) return;
  int s = ei[e];
  int d = ei[N_EDGES + e];
  float z = 0.5f * (s_node[s] + s_node[d]) + lin_b[0];
  out[e] = 1.f / (1.f + expf(-z));
}

extern "C" void kernel_launch(void* const* d_in, const int* in_sizes, int n_in,
                              void* d_out, int out_size, void* d_ws, size_t ws_size,
                              hipStream_t stream) {
  const float* x        = (const float*)d_in[0];
  const float* edge_attr= (const float*)d_in[1];
  const float* W        = (const float*)d_in[2];
  const float* W_edge   = (const float*)d_in[3];
  const float* att_src  = (const float*)d_in[4];
  const float* att_dst  = (const float*)d_in[5];
  const float* att_edge = (const float*)d_in[6];
  const float* bias     = (const float*)d_in[7];
  const float* lin_w    = (const float*)d_in[8];
  const float* lin_b    = (const float*)d_in[9];
  const int*   ei       = (const int*)d_in[10];
  float* out = (float*)d_out;

  // workspace layout
  float*    ws      = (float*)d_ws;
  float*    h       = ws;                               // N*H
  float*    a_src   = h + (size_t)N_NODES * HDIM;       // N
  float*    a_dst   = a_src + N_NODES;                  // N
  float*    s_node  = a_dst + N_NODES;                  // N
  float*    w_e     = s_node + N_NODES;                 // 16
  unsigned* deg     = (unsigned*)(w_e + 16);            // N (zeroed)
  unsigned* row_ptr = deg + N_NODES;                    // N
  int*      bsrc    = (int*)(row_ptr + N_NODES);        // E
  float*    bae     = (float*)(bsrc + N_EDGES);         // E
  // total ~ 25.6 + 2.0 + 12.8 MB = ~40.5 MB

  hipMemsetAsync(deg, 0, sizeof(unsigned) * N_NODES, stream);

  int nb_node   = (N_NODES + 3) / 4;     // wave per node
  int nb_edge_t = (N_EDGES + 255) / 256; // thread per edge

  k_node_h <<<nb_node, 256, 0, stream>>>(x, W, att_src, att_dst, h, a_src, a_dst);
  k_we     <<<1, 64, 0, stream>>>(W_edge, att_edge, w_e);
  k_deg    <<<nb_edge_t, 256, 0, stream>>>(ei, deg);
  k_scan   <<<1, 1024, 0, stream>>>(deg, row_ptr);
  k_bucket <<<nb_edge_t, 256, 0, stream>>>(edge_attr, ei, w_e, row_ptr, bsrc, bae);
  k_gather <<<nb_node, 256, 0, stream>>>(row_ptr, bsrc, bae, h, a_src, a_dst,
                                         bias, lin_w, s_node);
  k_out    <<<nb_edge_t, 256, 0, stream>>>(ei, s_node, lin_b, out);
}

// Round 3
// 646.203 us; speedup vs baseline: 1.2025x; 1.0081x over previous
//
#include <hip/hip_runtime.h>
#include <hip/hip_bf16.h>
#include <math.h>

#define N_NODES 100000
#define N_EDGES 1600000
#define F_IN 16
#define HDIM 64
#define E_DIM 9
#define NEG 0.2f

// ---- K1: h = x@W (wave per node) -> bf16; a_src/a_dst computed in fp32 ----
__global__ __launch_bounds__(256) void k_node_h(
    const float* __restrict__ x, const float* __restrict__ W,
    const float* __restrict__ att_src, const float* __restrict__ att_dst,
    __hip_bfloat16* __restrict__ hbf, float* __restrict__ a_src,
    float* __restrict__ a_dst) {
  __shared__ float sW[F_IN * HDIM];
  int t = threadIdx.x;
  for (int i = t; i < F_IN * HDIM; i += 256) sW[i] = W[i];
  __syncthreads();
  int lane = t & 63;
  int node = blockIdx.x * 4 + (t >> 6);
  if (node >= N_NODES) return;
  const float* xr = x + node * F_IN;
  float acc = 0.f;
#pragma unroll
  for (int k = 0; k < F_IN; ++k) acc += xr[k] * sW[k * HDIM + lane];
  hbf[(size_t)node * HDIM + lane] = __float2bfloat16(acc);
  float v1 = acc * att_src[lane];
  float v2 = acc * att_dst[lane];
#pragma unroll
  for (int off = 32; off > 0; off >>= 1) {
    v1 += __shfl_down(v1, off);
    v2 += __shfl_down(v2, off);
  }
  if (lane == 0) { a_src[node] = v1; a_dst[node] = v2; }
}

// ---- tiny: w_e[d] = sum_h W_edge[d,h]*att_edge[h] ----
__global__ void k_we(const float* __restrict__ W_edge,
                     const float* __restrict__ att_edge, float* __restrict__ w_e) {
  int d = threadIdx.x;
  if (d < E_DIM) {
    float s = 0.f;
    for (int hh = 0; hh < HDIM; ++hh) s += W_edge[d * HDIM + hh] * att_edge[hh];
    w_e[d] = s;
  }
}

// ---- K2: count in-degree (u32, 400 KB array -> L2-resident atomics) ----
__global__ __launch_bounds__(256) void k_deg(
    const int* __restrict__ ei, unsigned* __restrict__ deg) {
  int e = blockIdx.x * 256 + threadIdx.x;
  if (e >= N_EDGES) return;
  atomicAdd(deg + ei[N_EDGES + e], 1u);
}

// ---- K3: exclusive scan of deg -> row_ptr (single block, 1024 threads) ----
__global__ __launch_bounds__(1024) void k_scan(
    const unsigned* __restrict__ deg, unsigned* __restrict__ row_ptr) {
  const int T = 1024;
  const int chunk = (N_NODES + T - 1) / T;  // 98
  int t = threadIdx.x;
  int lane = t & 63, wid = t >> 6;
  int begin = t * chunk;
  int end = begin + chunk < N_NODES ? begin + chunk : N_NODES;
  unsigned local = 0;
  for (int i = begin; i < end; ++i) local += deg[i];
  unsigned v = local;
#pragma unroll
  for (int off = 1; off < 64; off <<= 1) {
    unsigned u = __shfl_up(v, off, 64);
    if (lane >= off) v += u;
  }
  __shared__ unsigned wsums[16];
  if (lane == 63) wsums[wid] = v;
  __syncthreads();
  if (t == 0) {
    unsigned a = 0;
    for (int i = 0; i < 16; ++i) { unsigned tmp = wsums[i]; wsums[i] = a; a += tmp; }
  }
  __syncthreads();
  unsigned run = wsums[wid] + v - local;
  for (int i = begin; i < end; ++i) { row_ptr[i] = run; run += deg[i]; }
}

// ---- K4: bucket edges by dst with FULL edge math done here (thread-per-edge).
// Stores packed {src, exp(leakyrelu(logit))} as one 8-B store. sum_ae via L2 atomic.
// After the pass row_ptr[d] = start of bucket d+1 (classic shift trick). ----
__global__ __launch_bounds__(256) void k_bucket(
    const float* __restrict__ ea, const int* __restrict__ ei,
    const float* __restrict__ w_e, const float* __restrict__ a_src,
    const float* __restrict__ a_dst, unsigned* __restrict__ row_ptr,
    uint2* __restrict__ bpack, float* __restrict__ sum_ae) {
  __shared__ float swe[E_DIM];
  if (threadIdx.x < E_DIM) swe[threadIdx.x] = w_e[threadIdx.x];
  __syncthreads();
  int e = blockIdx.x * 256 + threadIdx.x;
  if (e >= N_EDGES) return;
  int s = ei[e];
  int d = ei[N_EDGES + e];
  float a_e = 0.f;
#pragma unroll
  for (int k = 0; k < E_DIM; ++k) a_e += ea[e * E_DIM + k] * swe[k];
  float al = a_src[s] + a_dst[d] + a_e;
  al = al >= 0.f ? al : NEG * al;
  float ee = expf(al);  // shift-invariant softmax: max-subtract skipped
  unsigned pos = atomicAdd(row_ptr + d, 1u);
  bpack[pos] = make_uint2((unsigned)s, __float_as_uint(ee));
  atomicAdd(sum_ae + d, a_e);
}

// ---- K5: gather: denom + weighted bf16-h aggregate + self-loop + relu/lin_w ----
__global__ __launch_bounds__(256) void k_gather(
    const unsigned* __restrict__ row_ptr, const uint2* __restrict__ bpack,
    const __hip_bfloat16* __restrict__ hbf, const float* __restrict__ a_src,
    const float* __restrict__ a_dst, const float* __restrict__ sum_ae,
    const float* __restrict__ bias, const float* __restrict__ lin_w,
    float* __restrict__ s_node) {
  int t = threadIdx.x;
  int lane = t & 63;
  int node = blockIdx.x * 4 + (t >> 6);
  if (node >= N_NODES) return;
  unsigned start = node ? row_ptr[node - 1] : 0u;
  unsigned stop = row_ptr[node];
  float acc = 0.f, denom = 0.f;
  unsigned k = start;
  uint2 nxt;
  if (k < stop) nxt = bpack[k];
  while (k < stop) {
    uint2 cur = nxt;
    if (k + 1 < stop) nxt = bpack[k + 1];   // prefetch next packed edge
    float ee = __uint_as_float(cur.y);
    denom += ee;
    acc += ee * __bfloat162float(hbf[(size_t)cur.x * HDIM + lane]);
    ++k;
  }
  // self-loop (fill_value='mean'): logit uses mean of incident a_e
  float cnt = (float)(stop - start);
  float all = a_src[node] + a_dst[node] + sum_ae[node] / fmaxf(cnt, 1.f);
  all = all >= 0.f ? all : NEG * all;
  float eel = expf(all);
  denom += eel;
  acc += eel * __bfloat162float(hbf[(size_t)node * HDIM + lane]);
  float o = fmaxf(acc / (denom + 1e-16f) + bias[lane], 0.f) * lin_w[lane];
#pragma unroll
  for (int off = 32; off > 0; off >>= 1) o += __shfl_down(o, off);
  if (lane == 0) s_node[node] = o;
}

// ---- K6: out[e] = sigmoid(0.5*(s[src]+s[dst]) + lin_b) ----
__global__ __launch_bounds__(256) void k_out(
    const int* __restrict__ ei, const float* __restrict__ s_node,
    const float* __restrict__ lin_b, float* __restrict__ out) {
  int e = blockIdx.x * 256 + threadIdx.x;
  if (e >= N_EDGES) return;
  int s = ei[e];
  int d = ei[N_EDGES + e];
  float z = 0.5f * (s_node[s] + s_node[d]) + lin_b[0];
  out[e] = 1.f / (1.f + expf(-z));
}

extern "C" void kernel_launch(void* const* d_in, const int* in_sizes, int n_in,
                              void* d_out, int out_size, void* d_ws, size_t ws_size,
                              hipStream_t stream) {
  const float* x        = (const float*)d_in[0];
  const float* edge_attr= (const float*)d_in[1];
  const float* W        = (const float*)d_in[2];
  const float* W_edge   = (const float*)d_in[3];
  const float* att_src  = (const float*)d_in[4];
  const float* att_dst  = (const float*)d_in[5];
  const float* att_edge = (const float*)d_in[6];
  const float* bias     = (const float*)d_in[7];
  const float* lin_w    = (const float*)d_in[8];
  const float* lin_b    = (const float*)d_in[9];
  const int*   ei       = (const int*)d_in[10];
  float* out = (float*)d_out;

  // workspace layout (8-B alignment for bpack preserved: all offsets even)
  char* base = (char*)d_ws;
  __hip_bfloat16* hbf = (__hip_bfloat16*)base;                 // N*64*2 = 12.8 MB
  uint2* bpack  = (uint2*)(base + (size_t)N_NODES * HDIM * 2); // E*8   = 12.8 MB
  float* a_src  = (float*)(bpack + N_EDGES);                   // N
  float* a_dst  = a_src + N_NODES;                             // N
  float* s_node = a_dst + N_NODES;                             // N
  float* sum_ae = s_node + N_NODES;                            // N (zeroed)
  float* w_e    = sum_ae + N_NODES;                            // 16
  unsigned* deg     = (unsigned*)(w_e + 16);                   // N (zeroed)
  unsigned* row_ptr = deg + N_NODES;                           // N
  // total ~ 28.4 MB

  hipMemsetAsync(sum_ae, 0, sizeof(float) * N_NODES, stream);
  hipMemsetAsync(deg, 0, sizeof(unsigned) * N_NODES, stream);

  int nb_node   = (N_NODES + 3) / 4;
  int nb_edge_t = (N_EDGES + 255) / 256;

  k_node_h <<<nb_node, 256, 0, stream>>>(x, W, att_src, att_dst, hbf, a_src, a_dst);
  k_we     <<<1, 64, 0, stream>>>(W_edge, att_edge, w_e);
  k_deg    <<<nb_edge_t, 256, 0, stream>>>(ei, deg);
  k_scan   <<<1, 1024, 0, stream>>>(deg, row_ptr);
  k_bucket <<<nb_edge_t, 256, 0, stream>>>(edge_attr, ei, w_e, a_src, a_dst,
                                           row_ptr, bpack, sum_ae);
  k_gather <<<nb_node, 256, 0, stream>>>(row_ptr, bpack, hbf, a_src, a_dst,
                                         sum_ae, bias, lin_w, s_node);
  k_out    <<<nb_edge_t, 256, 0, stream>>>(ei, s_node, lin_b, out);
}

// Round 4
// 496.668 us; speedup vs baseline: 1.5645x; 1.3011x over previous
//
#include <hip/hip_runtime.h>
#include <hip/hip_bf16.h>
#include <math.h>

#define N_NODES 100000
#define N_EDGES 1600000
#define F_IN 16
#define HDIM 64
#define E_DIM 9
#define NEG 0.2f

#define N2 (N_NODES / 2)                 // 50000 uint2 elements of deg
#define SCAN_NB ((N2 + 255) / 256)       // 196 blocks, 512 deg entries each

// ---- K1: h = x@W (wave per node) -> bf16; a_src/a_dst computed in fp32 ----
__global__ __launch_bounds__(256) void k_node_h(
    const float* __restrict__ x, const float* __restrict__ W,
    const float* __restrict__ att_src, const float* __restrict__ att_dst,
    __hip_bfloat16* __restrict__ hbf, float* __restrict__ a_src,
    float* __restrict__ a_dst) {
  __shared__ float sW[F_IN * HDIM];
  int t = threadIdx.x;
  for (int i = t; i < F_IN * HDIM; i += 256) sW[i] = W[i];
  __syncthreads();
  int lane = t & 63;
  int node = blockIdx.x * 4 + (t >> 6);
  if (node >= N_NODES) return;
  const float* xr = x + node * F_IN;
  float acc = 0.f;
#pragma unroll
  for (int k = 0; k < F_IN; ++k) acc += xr[k] * sW[k * HDIM + lane];
  hbf[(size_t)node * HDIM + lane] = __float2bfloat16(acc);
  float v1 = acc * att_src[lane];
  float v2 = acc * att_dst[lane];
#pragma unroll
  for (int off = 32; off > 0; off >>= 1) {
    v1 += __shfl_down(v1, off);
    v2 += __shfl_down(v2, off);
  }
  if (lane == 0) { a_src[node] = v1; a_dst[node] = v2; }
}

// ---- tiny: w_e[d] = sum_h W_edge[d,h]*att_edge[h] ----
__global__ void k_we(const float* __restrict__ W_edge,
                     const float* __restrict__ att_edge, float* __restrict__ w_e) {
  int d = threadIdx.x;
  if (d < E_DIM) {
    float s = 0.f;
    for (int hh = 0; hh < HDIM; ++hh) s += W_edge[d * HDIM + hh] * att_edge[hh];
    w_e[d] = s;
  }
}

// ---- K2: count in-degree (u32, 400 KB array -> L2-resident atomics) ----
__global__ __launch_bounds__(256) void k_deg(
    const int* __restrict__ ei, unsigned* __restrict__ deg) {
  int e = blockIdx.x * 256 + threadIdx.x;
  if (e >= N_EDGES) return;
  atomicAdd(deg + ei[N_EDGES + e], 1u);
}

// ---- K3a: per-block sums of deg (512 entries/block, uint2 coalesced) ----
__global__ __launch_bounds__(256) void k_scan_part(
    const unsigned* __restrict__ deg, unsigned* __restrict__ blk) {
  int t = threadIdx.x;
  int idx2 = blockIdx.x * 256 + t;
  unsigned v = 0;
  if (idx2 < N2) { uint2 d2 = ((const uint2*)deg)[idx2]; v = d2.x + d2.y; }
#pragma unroll
  for (int off = 32; off > 0; off >>= 1) v += __shfl_down(v, off);
  __shared__ unsigned ws[4];
  if ((t & 63) == 0) ws[t >> 6] = v;
  __syncthreads();
  if (t == 0) blk[blockIdx.x] = ws[0] + ws[1] + ws[2] + ws[3];
}

// ---- K3b: exclusive scan of the 196 block sums (single block) ----
__global__ __launch_bounds__(256) void k_scan_blk(unsigned* __restrict__ blk) {
  int t = threadIdx.x;
  unsigned v = (t < SCAN_NB) ? blk[t] : 0u;
  int lane = t & 63, wid = t >> 6;
  unsigned incl = v;
#pragma unroll
  for (int off = 1; off < 64; off <<= 1) {
    unsigned u = __shfl_up(incl, off, 64);
    if (lane >= off) incl += u;
  }
  __shared__ unsigned ws[4];
  if (lane == 63) ws[wid] = incl;
  __syncthreads();
  if (t == 0) {
    unsigned a = 0;
    for (int i = 0; i < 4; ++i) { unsigned tmp = ws[i]; ws[i] = a; a += tmp; }
  }
  __syncthreads();
  if (t < SCAN_NB) blk[t] = ws[wid] + incl - v;  // exclusive prefix
}

// ---- K3c: full exclusive scan: block-local scan + block prefix ----
__global__ __launch_bounds__(256) void k_scan_full(
    const unsigned* __restrict__ deg, const unsigned* __restrict__ blk,
    unsigned* __restrict__ row_ptr) {
  int t = threadIdx.x;
  int idx2 = blockIdx.x * 256 + t;
  uint2 d2 = make_uint2(0u, 0u);
  if (idx2 < N2) d2 = ((const uint2*)deg)[idx2];
  unsigned s = d2.x + d2.y;
  int lane = t & 63, wid = t >> 6;
  unsigned incl = s;
#pragma unroll
  for (int off = 1; off < 64; off <<= 1) {
    unsigned u = __shfl_up(incl, off, 64);
    if (lane >= off) incl += u;
  }
  __shared__ unsigned ws[4];
  if (lane == 63) ws[wid] = incl;
  __syncthreads();
  if (t == 0) {
    unsigned a = 0;
    for (int i = 0; i < 4; ++i) { unsigned tmp = ws[i]; ws[i] = a; a += tmp; }
  }
  __syncthreads();
  unsigned pref = blk[blockIdx.x] + ws[wid] + incl - s;
  if (idx2 < N2) ((uint2*)row_ptr)[idx2] = make_uint2(pref, pref + d2.x);
}

// ---- K4: bucket edges by dst with FULL edge math done here (thread-per-edge).
// Stores packed {src, exp(leakyrelu(logit))} as one 8-B store. sum_ae via L2 atomic.
// After the pass row_ptr[d] = start of bucket d+1 (classic shift trick). ----
__global__ __launch_bounds__(256) void k_bucket(
    const float* __restrict__ ea, const int* __restrict__ ei,
    const float* __restrict__ w_e, const float* __restrict__ a_src,
    const float* __restrict__ a_dst, unsigned* __restrict__ row_ptr,
    uint2* __restrict__ bpack, float* __restrict__ sum_ae) {
  __shared__ float swe[E_DIM];
  if (threadIdx.x < E_DIM) swe[threadIdx.x] = w_e[threadIdx.x];
  __syncthreads();
  int e = blockIdx.x * 256 + threadIdx.x;
  if (e >= N_EDGES) return;
  int s = ei[e];
  int d = ei[N_EDGES + e];
  float a_e = 0.f;
#pragma unroll
  for (int k = 0; k < E_DIM; ++k) a_e += ea[e * E_DIM + k] * swe[k];
  float al = a_src[s] + a_dst[d] + a_e;
  al = al >= 0.f ? al : NEG * al;
  float ee = expf(al);  // shift-invariant softmax: max-subtract skipped
  unsigned pos = atomicAdd(row_ptr + d, 1u);
  bpack[pos] = make_uint2((unsigned)s, __float_as_uint(ee));
  atomicAdd(sum_ae + d, a_e);
}

// ---- K5: gather: denom + weighted bf16-h aggregate + self-loop + relu/lin_w ----
__global__ __launch_bounds__(256) void k_gather(
    const unsigned* __restrict__ row_ptr, const uint2* __restrict__ bpack,
    const __hip_bfloat16* __restrict__ hbf, const float* __restrict__ a_src,
    const float* __restrict__ a_dst, const float* __restrict__ sum_ae,
    const float* __restrict__ bias, const float* __restrict__ lin_w,
    float* __restrict__ s_node) {
  int t = threadIdx.x;
  int lane = t & 63;
  int node = blockIdx.x * 4 + (t >> 6);
  if (node >= N_NODES) return;
  unsigned start = node ? row_ptr[node - 1] : 0u;
  unsigned stop = row_ptr[node];
  float acc = 0.f, denom = 0.f;
  unsigned k = start;
  uint2 nxt;
  if (k < stop) nxt = bpack[k];
  while (k < stop) {
    uint2 cur = nxt;
    if (k + 1 < stop) nxt = bpack[k + 1];   // prefetch next packed edge
    float ee = __uint_as_float(cur.y);
    denom += ee;
    acc += ee * __bfloat162float(hbf[(size_t)cur.x * HDIM + lane]);
    ++k;
  }
  // self-loop (fill_value='mean'): logit uses mean of incident a_e
  float cnt = (float)(stop - start);
  float all = a_src[node] + a_dst[node] + sum_ae[node] / fmaxf(cnt, 1.f);
  all = all >= 0.f ? all : NEG * all;
  float eel = expf(all);
  denom += eel;
  acc += eel * __bfloat162float(hbf[(size_t)node * HDIM + lane]);
  float o = fmaxf(acc / (denom + 1e-16f) + bias[lane], 0.f) * lin_w[lane];
#pragma unroll
  for (int off = 32; off > 0; off >>= 1) o += __shfl_down(o, off);
  if (lane == 0) s_node[node] = o;
}

// ---- K6: out[e] = sigmoid(0.5*(s[src]+s[dst]) + lin_b) ----
__global__ __launch_bounds__(256) void k_out(
    const int* __restrict__ ei, const float* __restrict__ s_node,
    const float* __restrict__ lin_b, float* __restrict__ out) {
  int e = blockIdx.x * 256 + threadIdx.x;
  if (e >= N_EDGES) return;
  int s = ei[e];
  int d = ei[N_EDGES + e];
  float z = 0.5f * (s_node[s] + s_node[d]) + lin_b[0];
  out[e] = 1.f / (1.f + expf(-z));
}

extern "C" void kernel_launch(void* const* d_in, const int* in_sizes, int n_in,
                              void* d_out, int out_size, void* d_ws, size_t ws_size,
                              hipStream_t stream) {
  const float* x        = (const float*)d_in[0];
  const float* edge_attr= (const float*)d_in[1];
  const float* W        = (const float*)d_in[2];
  const float* W_edge   = (const float*)d_in[3];
  const float* att_src  = (const float*)d_in[4];
  const float* att_dst  = (const float*)d_in[5];
  const float* att_edge = (const float*)d_in[6];
  const float* bias     = (const float*)d_in[7];
  const float* lin_w    = (const float*)d_in[8];
  const float* lin_b    = (const float*)d_in[9];
  const int*   ei       = (const int*)d_in[10];
  float* out = (float*)d_out;

  // workspace layout (8-B alignment preserved: all element counts even)
  char* base = (char*)d_ws;
  __hip_bfloat16* hbf = (__hip_bfloat16*)base;                 // N*64*2 = 12.8 MB
  uint2* bpack  = (uint2*)(base + (size_t)N_NODES * HDIM * 2); // E*8   = 12.8 MB
  float* a_src  = (float*)(bpack + N_EDGES);                   // N
  float* a_dst  = a_src + N_NODES;                             // N
  float* s_node = a_dst + N_NODES;                             // N
  float* sum_ae = s_node + N_NODES;                            // N (zeroed)
  float* w_e    = sum_ae + N_NODES;                            // 16
  unsigned* deg     = (unsigned*)(w_e + 16);                   // N (zeroed)
  unsigned* row_ptr = deg + N_NODES;                           // N
  unsigned* blk     = row_ptr + N_NODES;                       // 256
  // total ~ 28.4 MB

  hipMemsetAsync(sum_ae, 0, sizeof(float) * N_NODES, stream);
  hipMemsetAsync(deg, 0, sizeof(unsigned) * N_NODES, stream);

  int nb_node   = (N_NODES + 3) / 4;
  int nb_edge_t = (N_EDGES + 255) / 256;

  k_node_h  <<<nb_node, 256, 0, stream>>>(x, W, att_src, att_dst, hbf, a_src, a_dst);
  k_we      <<<1, 64, 0, stream>>>(W_edge, att_edge, w_e);
  k_deg     <<<nb_edge_t, 256, 0, stream>>>(ei, deg);
  k_scan_part<<<SCAN_NB, 256, 0, stream>>>(deg, blk);
  k_scan_blk <<<1, 256, 0, stream>>>(blk);
  k_scan_full<<<SCAN_NB, 256, 0, stream>>>(deg, blk, row_ptr);
  k_bucket  <<<nb_edge_t, 256, 0, stream>>>(edge_attr, ei, w_e, a_src, a_dst,
                                            row_ptr, bpack, sum_ae);
  k_gather  <<<nb_node, 256, 0, stream>>>(row_ptr, bpack, hbf, a_src, a_dst,
                                          sum_ae, bias, lin_w, s_node);
  k_out     <<<nb_edge_t, 256, 0, stream>>>(ei, s_node, lin_b, out);
}

// Round 5
// 476.232 us; speedup vs baseline: 1.6317x; 1.0429x over previous
//
#include <hip/hip_runtime.h>
#include <hip/hip_bf16.h>
#include <math.h>

#define N_NODES 100000
#define N_EDGES 1600000
#define F_IN 16
#define HDIM 64
#define E_DIM 9
#define NEG 0.2f

#define N2 (N_NODES / 2)                 // 50000 uint2 elements of deg
#define SCAN_NB ((N2 + 255) / 256)       // 196 blocks, 512 deg entries each

// ---- K1: h = x@W (wave per node) -> bf16; a_src/a_dst computed in fp32 ----
__global__ __launch_bounds__(256) void k_node_h(
    const float* __restrict__ x, const float* __restrict__ W,
    const float* __restrict__ att_src, const float* __restrict__ att_dst,
    __hip_bfloat16* __restrict__ hbf, float* __restrict__ a_src,
    float* __restrict__ a_dst) {
  __shared__ float sW[F_IN * HDIM];
  int t = threadIdx.x;
  for (int i = t; i < F_IN * HDIM; i += 256) sW[i] = W[i];
  __syncthreads();
  int lane = t & 63;
  int node = blockIdx.x * 4 + (t >> 6);
  if (node >= N_NODES) return;
  const float* xr = x + node * F_IN;
  float acc = 0.f;
#pragma unroll
  for (int k = 0; k < F_IN; ++k) acc += xr[k] * sW[k * HDIM + lane];
  hbf[(size_t)node * HDIM + lane] = __float2bfloat16(acc);
  float v1 = acc * att_src[lane];
  float v2 = acc * att_dst[lane];
#pragma unroll
  for (int off = 32; off > 0; off >>= 1) {
    v1 += __shfl_down(v1, off);
    v2 += __shfl_down(v2, off);
  }
  if (lane == 0) { a_src[node] = v1; a_dst[node] = v2; }
}

// ---- tiny: w_e[d] = sum_h W_edge[d,h]*att_edge[h] ----
__global__ void k_we(const float* __restrict__ W_edge,
                     const float* __restrict__ att_edge, float* __restrict__ w_e) {
  int d = threadIdx.x;
  if (d < E_DIM) {
    float s = 0.f;
    for (int hh = 0; hh < HDIM; ++hh) s += W_edge[d * HDIM + hh] * att_edge[hh];
    w_e[d] = s;
  }
}

// ---- K2: count in-degree (nt load; u32 atomics into 400 KB L2-resident array) ----
__global__ __launch_bounds__(256) void k_deg(
    const int* __restrict__ ei, unsigned* __restrict__ deg) {
  int e = blockIdx.x * 256 + threadIdx.x;
  if (e >= N_EDGES) return;
  int d = __builtin_nontemporal_load(ei + N_EDGES + e);
  atomicAdd(deg + d, 1u);
}

// ---- K3a: per-block sums of deg (512 entries/block, uint2 coalesced) ----
__global__ __launch_bounds__(256) void k_scan_part(
    const unsigned* __restrict__ deg, unsigned* __restrict__ blk) {
  int t = threadIdx.x;
  int idx2 = blockIdx.x * 256 + t;
  unsigned v = 0;
  if (idx2 < N2) { uint2 d2 = ((const uint2*)deg)[idx2]; v = d2.x + d2.y; }
#pragma unroll
  for (int off = 32; off > 0; off >>= 1) v += __shfl_down(v, off);
  __shared__ unsigned ws[4];
  if ((t & 63) == 0) ws[t >> 6] = v;
  __syncthreads();
  if (t == 0) blk[blockIdx.x] = ws[0] + ws[1] + ws[2] + ws[3];
}

// ---- K3b: exclusive scan of the 196 block sums (single block) ----
__global__ __launch_bounds__(256) void k_scan_blk(unsigned* __restrict__ blk) {
  int t = threadIdx.x;
  unsigned v = (t < SCAN_NB) ? blk[t] : 0u;
  int lane = t & 63, wid = t >> 6;
  unsigned incl = v;
#pragma unroll
  for (int off = 1; off < 64; off <<= 1) {
    unsigned u = __shfl_up(incl, off, 64);
    if (lane >= off) incl += u;
  }
  __shared__ unsigned ws[4];
  if (lane == 63) ws[wid] = incl;
  __syncthreads();
  if (t == 0) {
    unsigned a = 0;
    for (int i = 0; i < 4; ++i) { unsigned tmp = ws[i]; ws[i] = a; a += tmp; }
  }
  __syncthreads();
  if (t < SCAN_NB) blk[t] = ws[wid] + incl - v;  // exclusive prefix
}

// ---- K3c: full exclusive scan: block-local scan + block prefix ----
__global__ __launch_bounds__(256) void k_scan_full(
    const unsigned* __restrict__ deg, const unsigned* __restrict__ blk,
    unsigned* __restrict__ row_ptr) {
  int t = threadIdx.x;
  int idx2 = blockIdx.x * 256 + t;
  uint2 d2 = make_uint2(0u, 0u);
  if (idx2 < N2) d2 = ((const uint2*)deg)[idx2];
  unsigned s = d2.x + d2.y;
  int lane = t & 63, wid = t >> 6;
  unsigned incl = s;
#pragma unroll
  for (int off = 1; off < 64; off <<= 1) {
    unsigned u = __shfl_up(incl, off, 64);
    if (lane >= off) incl += u;
  }
  __shared__ unsigned ws[4];
  if (lane == 63) ws[wid] = incl;
  __syncthreads();
  if (t == 0) {
    unsigned a = 0;
    for (int i = 0; i < 4; ++i) { unsigned tmp = ws[i]; ws[i] = a; a += tmp; }
  }
  __syncthreads();
  unsigned pref = blk[blockIdx.x] + ws[wid] + incl - s;
  if (idx2 < N2) ((uint2*)row_ptr)[idx2] = make_uint2(pref, pref + d2.x);
}

// ---- K4: bucket edges by dst; full edge math here (thread-per-edge).
// Streams (ei, edge_attr) via NT loads so L2 keeps the scatter lines.
// Stores packed u32 {src:17 | bf16(ee):15} — 4 B/edge scatter.
// After the pass row_ptr[d] = start of bucket d+1 (shift trick). ----
__global__ __launch_bounds__(256) void k_bucket(
    const float* __restrict__ ea, const int* __restrict__ ei,
    const float* __restrict__ w_e, const float* __restrict__ a_src,
    const float* __restrict__ a_dst, unsigned* __restrict__ row_ptr,
    unsigned* __restrict__ bpack, float* __restrict__ sum_ae) {
  __shared__ float swe[E_DIM];
  if (threadIdx.x < E_DIM) swe[threadIdx.x] = w_e[threadIdx.x];
  __syncthreads();
  int e = blockIdx.x * 256 + threadIdx.x;
  if (e >= N_EDGES) return;
  int s = __builtin_nontemporal_load(ei + e);
  int d = __builtin_nontemporal_load(ei + N_EDGES + e);
  float a_e = 0.f;
#pragma unroll
  for (int k = 0; k < E_DIM; ++k)
    a_e += __builtin_nontemporal_load(ea + (size_t)e * E_DIM + k) * swe[k];
  float al = a_src[s] + a_dst[d] + a_e;
  al = al >= 0.f ? al : NEG * al;
  float ee = expf(al);  // shift-invariant softmax: max-subtract skipped
  // round-to-nearest-even bf16; ee>0 so sign bit is free -> 15 bits
  unsigned b = __float_as_uint(ee);
  b += 0x7fffu + ((b >> 16) & 1u);
  unsigned pk = ((unsigned)s << 15) | ((b >> 16) & 0x7fffu);
  unsigned pos = atomicAdd(row_ptr + d, 1u);
  bpack[pos] = pk;
  atomicAdd(sum_ae + d, a_e);
}

// ---- K5: gather: denom + weighted bf16-h aggregate + self-loop + relu/lin_w.
// 4-way unrolled: 4 independent h-gathers in flight per wave. ----
__global__ __launch_bounds__(256) void k_gather(
    const unsigned* __restrict__ row_ptr, const unsigned* __restrict__ bpack,
    const __hip_bfloat16* __restrict__ hbf, const float* __restrict__ a_src,
    const float* __restrict__ a_dst, const float* __restrict__ sum_ae,
    const float* __restrict__ bias, const float* __restrict__ lin_w,
    float* __restrict__ s_node) {
  int t = threadIdx.x;
  int lane = t & 63;
  int node = blockIdx.x * 4 + (t >> 6);
  if (node >= N_NODES) return;
  unsigned start = node ? row_ptr[node - 1] : 0u;
  unsigned stop = row_ptr[node];
  float acc = 0.f, denom = 0.f;
  unsigned k = start;
  for (; k + 4 <= stop; k += 4) {
    unsigned p0 = __builtin_nontemporal_load(bpack + k);
    unsigned p1 = __builtin_nontemporal_load(bpack + k + 1);
    unsigned p2 = __builtin_nontemporal_load(bpack + k + 2);
    unsigned p3 = __builtin_nontemporal_load(bpack + k + 3);
    float e0 = __uint_as_float((p0 & 0x7fffu) << 16);
    float e1 = __uint_as_float((p1 & 0x7fffu) << 16);
    float e2 = __uint_as_float((p2 & 0x7fffu) << 16);
    float e3 = __uint_as_float((p3 & 0x7fffu) << 16);
    float h0 = __bfloat162float(hbf[(size_t)(p0 >> 15) * HDIM + lane]);
    float h1 = __bfloat162float(hbf[(size_t)(p1 >> 15) * HDIM + lane]);
    float h2 = __bfloat162float(hbf[(size_t)(p2 >> 15) * HDIM + lane]);
    float h3 = __bfloat162float(hbf[(size_t)(p3 >> 15) * HDIM + lane]);
    denom += (e0 + e1) + (e2 + e3);
    acc += e0 * h0 + e1 * h1 + e2 * h2 + e3 * h3;
  }
  for (; k < stop; ++k) {
    unsigned p = __builtin_nontemporal_load(bpack + k);
    float ee = __uint_as_float((p & 0x7fffu) << 16);
    denom += ee;
    acc += ee * __bfloat162float(hbf[(size_t)(p >> 15) * HDIM + lane]);
  }
  // self-loop (fill_value='mean'): logit uses mean of incident a_e
  float cnt = (float)(stop - start);
  float all = a_src[node] + a_dst[node] + sum_ae[node] / fmaxf(cnt, 1.f);
  all = all >= 0.f ? all : NEG * all;
  float eel = expf(all);
  denom += eel;
  acc += eel * __bfloat162float(hbf[(size_t)node * HDIM + lane]);
  float o = fmaxf(acc / (denom + 1e-16f) + bias[lane], 0.f) * lin_w[lane];
#pragma unroll
  for (int off = 32; off > 0; off >>= 1) o += __shfl_down(o, off);
  if (lane == 0) s_node[node] = o;
}

// ---- K6: out[e] = sigmoid(0.5*(s[src]+s[dst]) + lin_b) ----
__global__ __launch_bounds__(256) void k_out(
    const int* __restrict__ ei, const float* __restrict__ s_node,
    const float* __restrict__ lin_b, float* __restrict__ out) {
  int e = blockIdx.x * 256 + threadIdx.x;
  if (e >= N_EDGES) return;
  int s = __builtin_nontemporal_load(ei + e);
  int d = __builtin_nontemporal_load(ei + N_EDGES + e);
  float z = 0.5f * (s_node[s] + s_node[d]) + lin_b[0];
  float r = 1.f / (1.f + expf(-z));
  __builtin_nontemporal_store(r, out + e);
}

extern "C" void kernel_launch(void* const* d_in, const int* in_sizes, int n_in,
                              void* d_out, int out_size, void* d_ws, size_t ws_size,
                              hipStream_t stream) {
  const float* x        = (const float*)d_in[0];
  const float* edge_attr= (const float*)d_in[1];
  const float* W        = (const float*)d_in[2];
  const float* W_edge   = (const float*)d_in[3];
  const float* att_src  = (const float*)d_in[4];
  const float* att_dst  = (const float*)d_in[5];
  const float* att_edge = (const float*)d_in[6];
  const float* bias     = (const float*)d_in[7];
  const float* lin_w    = (const float*)d_in[8];
  const float* lin_b    = (const float*)d_in[9];
  const int*   ei       = (const int*)d_in[10];
  float* out = (float*)d_out;

  // workspace layout (8-B alignment preserved)
  char* base = (char*)d_ws;
  __hip_bfloat16* hbf = (__hip_bfloat16*)base;                    // N*64*2 = 12.8 MB
  unsigned* bpack = (unsigned*)(base + (size_t)N_NODES * HDIM * 2); // E*4  = 6.4 MB
  float* a_src  = (float*)(bpack + N_EDGES);                      // N
  float* a_dst  = a_src + N_NODES;                                // N
  float* s_node = a_dst + N_NODES;                                // N
  float* sum_ae = s_node + N_NODES;                               // N (zeroed)
  float* w_e    = sum_ae + N_NODES;                               // 16
  unsigned* deg     = (unsigned*)(w_e + 16);                      // N (zeroed)
  unsigned* row_ptr = deg + N_NODES;                              // N
  unsigned* blk     = row_ptr + N_NODES;                          // 256
  // total ~ 22 MB

  hipMemsetAsync(sum_ae, 0, sizeof(float) * N_NODES, stream);
  hipMemsetAsync(deg, 0, sizeof(unsigned) * N_NODES, stream);

  int nb_node   = (N_NODES + 3) / 4;
  int nb_edge_t = (N_EDGES + 255) / 256;

  k_node_h  <<<nb_node, 256, 0, stream>>>(x, W, att_src, att_dst, hbf, a_src, a_dst);
  k_we      <<<1, 64, 0, stream>>>(W_edge, att_edge, w_e);
  k_deg     <<<nb_edge_t, 256, 0, stream>>>(ei, deg);
  k_scan_part<<<SCAN_NB, 256, 0, stream>>>(deg, blk);
  k_scan_blk <<<1, 256, 0, stream>>>(blk);
  k_scan_full<<<SCAN_NB, 256, 0, stream>>>(deg, blk, row_ptr);
  k_bucket  <<<nb_edge_t, 256, 0, stream>>>(edge_attr, ei, w_e, a_src, a_dst,
                                            row_ptr, bpack, sum_ae);
  k_gather  <<<nb_node, 256, 0, stream>>>(row_ptr, bpack, hbf, a_src, a_dst,
                                          sum_ae, bias, lin_w, s_node);
  k_out     <<<nb_edge_t, 256, 0, stream>>>(ei, s_node, lin_b, out);
}